// Round 12
// baseline (2824.075 us; speedup 1.0000x reference)
//
#include <hip/hip_runtime.h>
#include <hip/hip_bf16.h>
#include <stdint.h>
#include <float.h>

typedef unsigned int uint;

#define NB 8
#define NPTS 4096
#define NS 512
#define NKN 32

// ---- static device scratch (~105 MB, allocated at module load; fully rewritten each call)
__device__ int   g_fps_idx[NB*NS];
__device__ int   g_knn_idx[NB*NS*NKN];
__device__ float g_knn_d2 [NB*NS*NKN];
__device__ float g_posb   [(size_t)NB*NS*NKN*64];   // 32 MB
__device__ float g_ga     [(size_t)NB*NS*NS];       //  8 MB
__device__ float g_grpb   [(size_t)NB*NS*NKN*128];  // 64 MB

__device__ __forceinline__ unsigned long long shfl_down_u64(unsigned long long v, int off){
  int lo = __shfl_down((int)(unsigned)v, off);
  int hi = __shfl_down((int)(unsigned)(v >> 32), off);
  return ((unsigned long long)(unsigned)hi << 32) | (unsigned)lo;
}
__device__ __forceinline__ double shfl_down_f64(double v, int off){
  return __longlong_as_double((long long)shfl_down_u64((unsigned long long)__double_as_longlong(v), off));
}
__device__ __forceinline__ void ldf8(const float* p, float* d){
  float4 a = *(const float4*)p, b = *(const float4*)(p+4);
  d[0]=a.x; d[1]=a.y; d[2]=a.z; d[3]=a.w; d[4]=b.x; d[5]=b.y; d[6]=b.z; d[7]=b.w;
}
// robust start read: int32 (start[b]) vs int64 (start[2b]; high words zero since values<4096)
__device__ __forceinline__ int read_start(const int* __restrict__ start, int b){
  int w1 = start[1], w3 = start[3], w5 = start[5], w7 = start[7];
  bool is64 = ((w1 | w3 | w5 | w7) == 0);
  int v = is64 ? start[2*b] : start[b];
  return v & (NPTS - 1);
}

// flat column order: n = k*128 + d, d<64 -> posb, d>=64 -> points gather
__device__ __forceinline__ void load_flat8(const float* __restrict__ points,
                                           int b, int row, int n, float* d){
  const int k = n >> 7, col = n & 63;
  if (n & 64){
    const int idx = g_knn_idx[((b << 9) + row)*32 + k];
    ldf8(points + (((size_t)b << 12) + idx)*64 + col, d);
  } else {
    ldf8(g_posb + (((size_t)((b << 9) + row))*32 + k)*64 + col, d);
  }
}
// reorganized order for Gram only: kc in [0,2048) pos (k-major), [2048,4096) pts
__device__ __forceinline__ void load_gram8(const float* __restrict__ points,
                                           int b, int row, int kc, float* d){
  if (kc < 2048){
    ldf8(g_posb + ((size_t)((b << 9) + row))*2048 + kc, d);
  } else {
    const int kc2 = kc - 2048, kg = kc2 >> 6, col = kc2 & 63;
    const int idx = g_knn_idx[((b << 9) + row)*32 + kg];
    ldf8(points + (((size_t)b << 12) + idx)*64 + col, d);
  }
}

// ---------------------------------------------------------------- FPS (f64 selection) -> f32 out
__global__ __launch_bounds__(256) void k_fps(const float* __restrict__ xyz,
                                             const int* __restrict__ start,
                                             float* __restrict__ center_out){
#pragma clang fp contract(off)
  const int b = blockIdx.x, tid = threadIdx.x;
  const float* X = xyz + (size_t)b * NPTS * 3;
  __shared__ float sx[NPTS], sy[NPTS], sz[NPTS];
  for (int p = tid; p < NPTS; p += 256){
    sx[p] = X[3*p]; sy[p] = X[3*p+1]; sz[p] = X[3*p+2];
  }
  __shared__ int s_start0;
  if (tid == 0) s_start0 = read_start(start, b);
  __syncthreads();
  float px[16], py[16], pz[16];
  double dist[16];
  for (int i = 0; i < 16; i++){
    int p = tid*16 + i;
    px[i] = sx[p]; py[i] = sy[p]; pz[i] = sz[p];
    dist[i] = 1e10;
  }
  __shared__ double s_v[4]; __shared__ int s_i[4]; __shared__ int s_cur;
  int cur = s_start0;
  for (int t = 0; t < NS; t++){
    if (tid == 0){
      g_fps_idx[b*NS + t] = cur;
      center_out[(size_t)(b*NS + t)*3 + 0] = sx[cur];
      center_out[(size_t)(b*NS + t)*3 + 1] = sy[cur];
      center_out[(size_t)(b*NS + t)*3 + 2] = sz[cur];
    }
    const double cx = (double)sx[cur], cy = (double)sy[cur], cz = (double)sz[cur];
    double bv = -1.0; int bi = 0;
    for (int i = 0; i < 16; i++){
      double dx = (double)px[i]-cx, dy = (double)py[i]-cy, dz = (double)pz[i]-cz;
      double d = ((dx*dx) + (dy*dy)) + (dz*dz);
      dist[i] = fmin(dist[i], d);
      if (dist[i] > bv){ bv = dist[i]; bi = tid*16 + i; }
    }
    for (int off = 32; off; off >>= 1){
      double ov = shfl_down_f64(bv, off); int oi = __shfl_down(bi, off);
      if (ov > bv || (ov == bv && oi < bi)){ bv = ov; bi = oi; }
    }
    if ((tid & 63) == 0){ s_v[tid>>6] = bv; s_i[tid>>6] = bi; }
    __syncthreads();
    if (tid == 0){
      double vv = s_v[0]; int ii = s_i[0];
      for (int w = 1; w < 4; w++){
        if (s_v[w] > vv || (s_v[w] == vv && s_i[w] < ii)){ vv = s_v[w]; ii = s_i[w]; }
      }
      s_cur = ii;
    }
    __syncthreads();
    cur = s_cur;
  }
}

// ---------------------------------------------------------------- KNN top-32 (f64, lexicographic (d2,idx))
__global__ __launch_bounds__(256) void k_knn(const float* __restrict__ xyz){
#pragma clang fp contract(off)
  const int g = blockIdx.x;            // b*512 + s
  const int b = g >> 9;
  const int tid = threadIdx.x;
  const float* X = xyz + (size_t)b * NPTS * 3;
  const int cidx = g_fps_idx[g];
  const double cx = (double)X[3*cidx], cy = (double)X[3*cidx+1], cz = (double)X[3*cidx+2];
  const double cs = ((cx*cx) + (cy*cy)) + (cz*cz);
  double dl[16];
  for (int i = 0; i < 16; i++){
    int p = tid*16 + i;
    double x = (double)X[3*p], y = (double)X[3*p+1], z = (double)X[3*p+2];
    double xs = ((x*x) + (y*y)) + (z*z);
    double dt = ((cx*x) + (cy*y)) + (cz*z);
    dl[i] = (cs + xs) - 2.0*dt;
  }
  __shared__ double s_kd[4]; __shared__ int s_ki[4];
  __shared__ double s_wd;   __shared__ int s_wi;
  double lastd = -DBL_MAX; int lasti = -1;
  for (int sel = 0; sel < NKN; sel++){
    double bd = DBL_MAX; int bi = 0x7fffffff;
    for (int i = 0; i < 16; i++){
      int p = tid*16 + i;
      double d = dl[i];
      bool gt_last = (d > lastd) || (d == lastd && p > lasti);
      bool lt_best = (d < bd)    || (d == bd    && p < bi);
      if (gt_last && lt_best){ bd = d; bi = p; }
    }
    for (int off = 32; off; off >>= 1){
      double od = shfl_down_f64(bd, off); int oi = __shfl_down(bi, off);
      if (od < bd || (od == bd && oi < bi)){ bd = od; bi = oi; }
    }
    if ((tid & 63) == 0){ s_kd[tid>>6] = bd; s_ki[tid>>6] = bi; }
    __syncthreads();
    if (tid == 0){
      double md = s_kd[0]; int mi = s_ki[0];
      for (int w = 1; w < 4; w++){
        if (s_kd[w] < md || (s_kd[w] == md && s_ki[w] < mi)){ md = s_kd[w]; mi = s_ki[w]; }
      }
      s_wd = md; s_wi = mi;
      g_knn_idx[g*NKN + sel] = mi;
      g_knn_d2 [g*NKN + sel] = (float)md;
    }
    __syncthreads();
    lastd = s_wd; lasti = s_wi;
    __syncthreads();
  }
}

// ---------------------------------------------------------------- pos-embed MLP -> g_posb (f32)
__global__ __launch_bounds__(256) void k_posembed(
    const float* __restrict__ xyz,
    const float* __restrict__ w1, const float* __restrict__ b1, const float* __restrict__ bn1,
    const float* __restrict__ w2, const float* __restrict__ b2, const float* __restrict__ bn2){
  __shared__ float w1s[320], a1s[32], d1s[32], w2s[2048], a2s[64], d2s[64];
  const int t = threadIdx.x;
  for (int i = t; i < 320; i += 256) w1s[i] = w1[i];
  for (int i = t; i < 2048; i += 256) w2s[i] = w2[i];
  if (t < 32){
    float g = bn1[t], be = bn1[32+t], m = bn1[64+t], v = bn1[96+t];
    float a = g * rsqrtf(v + 1e-5f);
    a1s[t] = a; d1s[t] = b1[t]*a + (be - m*a);
  }
  if (t < 64){
    float g = bn2[t], be = bn2[64+t], m = bn2[128+t], v = bn2[192+t];
    float a = g * rsqrtf(v + 1e-5f);
    a2s[t] = a; d2s[t] = b2[t]*a + (be - m*a);
  }
  __syncthreads();
  const int row = blockIdx.x*256 + t;          // (b*512+s)*32 + k
  const int b = row >> 14;
  const int g = row >> 5;
  const float* X = xyz + (size_t)b * NPTS * 3;
  const int ci = g_fps_idx[g];
  const int ni = g_knn_idx[row];
  float c0 = X[3*ci], c1 = X[3*ci+1], c2 = X[3*ci+2];
  float n0 = X[3*ni], n1 = X[3*ni+1], n2 = X[3*ni+2];
  float feat[10] = {c0,c1,c2, n0,n1,n2, n0-c0,n1-c1,n2-c2, g_knn_d2[row]};
  float h[32];
  for (int o = 0; o < 32; o++){
    float acc = 0.f;
    for (int j = 0; j < 10; j++) acc += feat[j]*w1s[j*32+o];
    h[o] = fmaxf(acc*a1s[o] + d1s[o], 0.f);
  }
  float* xr = g_posb + (size_t)row * 64;
  for (int o = 0; o < 64; o++){
    float acc = 0.f;
    for (int j = 0; j < 32; j++) acc += h[j]*w2s[j*64+o];
    xr[o] = fmaxf(acc*a2s[o] + d2s[o], 0.f);
  }
}

// ---------------------------------------------------------------- Gram = flat @ flat^T (f32)
__global__ __launch_bounds__(256) void k_gram(const float* __restrict__ points){
  const int b = blockIdx.y;
  const int i0 = (blockIdx.x >> 3) * 64, j0 = (blockIdx.x & 7) * 64;
  __shared__ float As[32][68];
  __shared__ float Bs[32][68];
  const int t = threadIdx.x, tx = t & 15, ty = t >> 4;
  float acc[4][4] = {};
  for (int k0 = 0; k0 < 4096; k0 += 32){
    {
      int r = t >> 2, kk = (t & 3) * 8;
      float ta[8], tb[8];
      load_gram8(points, b, i0+r, k0+kk, ta);
      load_gram8(points, b, j0+r, k0+kk, tb);
      for (int jj = 0; jj < 8; jj++){ As[kk+jj][r] = ta[jj]; Bs[kk+jj][r] = tb[jj]; }
    }
    __syncthreads();
    for (int kk = 0; kk < 32; kk++){
      const float4 a4 = *(const float4*)(&As[kk][ty*4]);
      const float4 b4 = *(const float4*)(&Bs[kk][tx*4]);
      const float ar[4] = {a4.x,a4.y,a4.z,a4.w};
      const float br[4] = {b4.x,b4.y,b4.z,b4.w};
      for (int ia = 0; ia < 4; ia++)
        for (int ib = 0; ib < 4; ib++) acc[ia][ib] += ar[ia]*br[ib];
    }
    __syncthreads();
  }
  float* C = g_ga + (size_t)b * NS * NS;
  for (int ia = 0; ia < 4; ia++){
    float4 o = {acc[ia][0], acc[ia][1], acc[ia][2], acc[ia][3]};
    *(float4*)(C + (size_t)(i0+ty*4+ia)*NS + j0 + tx*4) = o;
  }
}

// ---------------------------------------------------------------- row softmax (in place)
__global__ __launch_bounds__(256) void k_softmax(){
  float* R = g_ga + (size_t)blockIdx.x * NS;
  const int t = threadIdx.x;
  float v0 = R[t], v1 = R[t+256];
  __shared__ float sm[4], ssum[4];
  float m = fmaxf(v0, v1);
  for (int off = 32; off; off >>= 1) m = fmaxf(m, __shfl_down(m, off));
  if ((t & 63) == 0) sm[t>>6] = m;
  __syncthreads();
  float mm = fmaxf(fmaxf(sm[0], sm[1]), fmaxf(sm[2], sm[3]));
  float e0 = expf(v0 - mm), e1 = expf(v1 - mm);
  float s = e0 + e1;
  for (int off = 32; off; off >>= 1) s += __shfl_down(s, off);
  if ((t & 63) == 0) ssum[t>>6] = s;
  __syncthreads();
  float inv = 1.0f / (ssum[0]+ssum[1]+ssum[2]+ssum[3]);
  R[t] = e0*inv; R[t+256] = e1*inv;
}

// ---------------------------------------------------------------- grp_raw = ga @ flat -> g_grpb (f32)
__global__ __launch_bounds__(256) void k_grp(const float* __restrict__ points){
  const int b = blockIdx.y;
  const int s0 = (blockIdx.x >> 6) * 64, n0 = (blockIdx.x & 63) * 64;
  const float* G = g_ga + (size_t)b * NS * NS;
  __shared__ float As[32][68];
  __shared__ float Bs[32][68];
  const int t = threadIdx.x, tx = t & 15, ty = t >> 4;
  float acc[4][4] = {};
  for (int k0 = 0; k0 < NS; k0 += 32){
    {
      int r = t >> 2, kk = (t & 3) * 8;
      const float* pa = G + (size_t)(s0+r)*NS + k0 + kk;
      float4 v0 = *(const float4*)pa, v1 = *(const float4*)(pa+4);
      As[kk+0][r]=v0.x; As[kk+1][r]=v0.y; As[kk+2][r]=v0.z; As[kk+3][r]=v0.w;
      As[kk+4][r]=v1.x; As[kk+5][r]=v1.y; As[kk+6][r]=v1.z; As[kk+7][r]=v1.w;
      int k2 = t >> 3, c = (t & 7) * 8;
      float tb[8];
      load_flat8(points, b, k0+k2, n0+c, tb);
      for (int jj = 0; jj < 8; jj++) Bs[k2][c+jj] = tb[jj];
    }
    __syncthreads();
    for (int kk = 0; kk < 32; kk++){
      const float4 a4 = *(const float4*)(&As[kk][ty*4]);
      const float4 b4 = *(const float4*)(&Bs[kk][tx*4]);
      const float ar[4] = {a4.x,a4.y,a4.z,a4.w};
      const float br[4] = {b4.x,b4.y,b4.z,b4.w};
      for (int ia = 0; ia < 4; ia++)
        for (int ib = 0; ib < 4; ib++) acc[ia][ib] += ar[ia]*br[ib];
    }
    __syncthreads();
  }
  const int n = n0 + tx*4;
  const int kq = n >> 7, dq = n & 127;
  for (int ia = 0; ia < 4; ia++){
    int s = s0 + ty*4 + ia;
    float4 o = {acc[ia][0], acc[ia][1], acc[ia][2], acc[ia][3]};
    *(float4*)(g_grpb + (((size_t)(b*NS + s))*32 + kq)*128 + dq) = o;
  }
}

// ---------------------------------------------------------------- fused NSA + cat MLP + shortcut + maxpool -> f32 out
__global__ __launch_bounds__(256) void k_final(
    const float* __restrict__ points,
    const float* __restrict__ wq, const float* __restrict__ bq,
    const float* __restrict__ wk, const float* __restrict__ bk,
    const float* __restrict__ wv, const float* __restrict__ bv,
    const float* __restrict__ nsa_g, const float* __restrict__ gam_g,
    const float* __restrict__ w1, const float* __restrict__ b1, const float* __restrict__ bn1,
    const float* __restrict__ w2, const float* __restrict__ b2, const float* __restrict__ bn2,
    const float* __restrict__ wsc, const float* __restrict__ bsc, const float* __restrict__ bnsc,
    float* __restrict__ out){
  const int g = blockIdx.y*512 + blockIdx.x;    // group = b*512+s
  const int t = threadIdx.x, b = g >> 9;
  __shared__ float xs[32][132];          // x rows
  __shared__ float dsf[32][260];         // dsa rows (f32)
  __shared__ float hsbuf[32*260];        // phase B: vs/qs/ks/at overlay; phase C: h
  __shared__ float a1s[256], d1s[256];
  __shared__ float red[256];
  float* vs = hsbuf;                     // [32][132]
  float* qs = hsbuf + 4224;              // [32][16]
  float* ks = hsbuf + 4736;              // [32][16]
  float* at = hsbuf + 5248;              // [32][33]
  // ---- phase A
  {
    int r = t >> 3, c8 = (t & 7) * 8;
    float tmp[8];
    ldf8(g_posb + ((size_t)g*32 + r)*64 + c8, tmp);
    for (int j = 0; j < 8; j++) xs[r][c8+j] = tmp[j];
    int idx = g_knn_idx[g*32 + r];
    ldf8(points + ((size_t)b*NPTS + idx)*64 + c8, tmp);
    for (int j = 0; j < 8; j++) xs[r][64+c8+j] = tmp[j];
  }
  {
    float gg2 = bn1[t], be = bn1[256+t], m = bn1[512+t], v = bn1[768+t];
    float a = gg2 * rsqrtf(v + 1e-5f);
    a1s[t] = a; d1s[t] = b1[t]*a + (be - m*a);
  }
  __syncthreads();
  const float gmn = nsa_g[0], gmg = gam_g[0];
  // ---- phase B0: grp -> dsa right half ; Q/K ; V
  {
    int r = t >> 3, c16 = (t & 7) * 16;
    const float* gp = g_grpb + ((size_t)g*32 + r)*128 + c16;
    for (int j = 0; j < 16; j++)
      dsf[r][128+c16+j] = gmg*gp[j] + xs[r][c16+j];
  }
  {
    int r = t >> 3, c = t & 7;
    float aq0 = bq[c], aq1 = bq[c+8], ak0 = bk[c], ak1 = bk[c+8];
    for (int j = 0; j < 128; j++){
      float xv = xs[r][j];
      aq0 += xv * wq[j*16+c];
      aq1 += xv * wq[j*16+c+8];
      ak0 += xv * wk[j*16+c];
      ak1 += xv * wk[j*16+c+8];
    }
    qs[r*16+c] = aq0; qs[r*16+c+8] = aq1; ks[r*16+c] = ak0; ks[r*16+c+8] = ak1;
  }
  {
    int r = t >> 3, cb = (t & 7) * 16;
    float acc[16];
    for (int i = 0; i < 16; i++) acc[i] = bv[cb+i];
    for (int j = 0; j < 128; j++){
      float xv = xs[r][j];
      const float4* w4 = (const float4*)(wv + j*128 + cb);
      float4 wa = w4[0], wb = w4[1], wc = w4[2], wd = w4[3];
      acc[0] += xv*wa.x;  acc[1] += xv*wa.y;  acc[2] += xv*wa.z;  acc[3] += xv*wa.w;
      acc[4] += xv*wb.x;  acc[5] += xv*wb.y;  acc[6] += xv*wb.z;  acc[7] += xv*wb.w;
      acc[8] += xv*wc.x;  acc[9] += xv*wc.y;  acc[10]+= xv*wc.z;  acc[11]+= xv*wc.w;
      acc[12]+= xv*wd.x;  acc[13]+= xv*wd.y;  acc[14]+= xv*wd.z;  acc[15]+= xv*wd.w;
    }
    for (int i = 0; i < 16; i++) vs[r*132 + cb + i] = acc[i];
  }
  __syncthreads();
  // ---- phase B1: attn logits + softmax
  {
    int r = t >> 3, jb = (t & 7) * 4;
    for (int jj = 0; jj < 4; jj++){
      int j = jb + jj; float acc = 0.f;
      for (int c = 0; c < 16; c++) acc += qs[r*16+c] * ks[j*16+c];
      at[r*33 + j] = acc;
    }
  }
  __syncthreads();
  if (t < 32){
    float m = -1e30f;
    for (int j = 0; j < 32; j++) m = fmaxf(m, at[t*33+j]);
    float e[32]; float sum = 0.f;
    for (int j = 0; j < 32; j++){ e[j] = expf(at[t*33+j] - m); sum += e[j]; }
    float inv = 1.0f / sum;
    for (int j = 0; j < 32; j++) at[t*33+j] = e[j]*inv;
  }
  __syncthreads();
  // ---- phase B2: PV -> nei -> dsa left half
  {
    int r = t >> 3, cb = (t & 7) * 16;
    float acc[16] = {};
    for (int j = 0; j < 32; j++){
      float a = at[r*33+j];
      for (int i = 0; i < 16; i++) acc[i] += a * vs[j*132 + cb + i];
    }
    for (int i = 0; i < 16; i++)
      dsf[r][cb+i] = gmn*acc[i] + xs[r][cb+i];
  }
  __syncthreads();
  // ---- phase C1: h = relu(bn1(dsa @ W1 + b1))
  {
    const int kg = t >> 6, c0 = (t & 63) * 4;
    float acc[8][4] = {};
    for (int j = 0; j < 256; j += 4){
      float wvv[4][4];
      for (int jj = 0; jj < 4; jj++){
        float4 wrow = *(const float4*)(w1 + (j+jj)*256 + c0);
        wvv[jj][0] = wrow.x; wvv[jj][1] = wrow.y; wvv[jj][2] = wrow.z; wvv[jj][3] = wrow.w;
      }
      for (int r = 0; r < 8; r++){
        const float4 d4 = *(const float4*)(&dsf[kg*8+r][j]);
        const float dr[4] = {d4.x, d4.y, d4.z, d4.w};
        for (int jj = 0; jj < 4; jj++)
          for (int i = 0; i < 4; i++) acc[r][i] += dr[jj]*wvv[jj][i];
      }
    }
    for (int r = 0; r < 8; r++){
      float4 o;
      o.x = fmaxf(acc[r][0]*a1s[c0+0] + d1s[c0+0], 0.f);
      o.y = fmaxf(acc[r][1]*a1s[c0+1] + d1s[c0+1], 0.f);
      o.z = fmaxf(acc[r][2]*a1s[c0+2] + d1s[c0+2], 0.f);
      o.w = fmaxf(acc[r][3]*a1s[c0+3] + d1s[c0+3], 0.f);
      *(float4*)(&hsbuf[(kg*8+r)*260 + c0]) = o;
    }
  }
  __syncthreads();
  // ---- phase C2: layer 2 + shortcut + relu + max over k
  {
    const int c = t & 127, kh = t >> 7;
    float g2 = bn2[c], be2 = bn2[128+c], m2 = bn2[256+c], v2 = bn2[384+c];
    float a2 = g2 * rsqrtf(v2 + 1e-5f);
    float d2v = b2[c]*a2 + (be2 - m2*a2);
    float gsc = bnsc[c], besc = bnsc[128+c], msc = bnsc[256+c], vsc = bnsc[384+c];
    float asc = gsc * rsqrtf(vsc + 1e-5f);
    float dscv = bsc[c]*asc + (besc - msc*asc);
    float accm[16] = {};
    for (int j = 0; j < 256; j += 4){
      float w0 = w2[j*128+c], w1v = w2[(j+1)*128+c];
      float w2v = w2[(j+2)*128+c], w3 = w2[(j+3)*128+c];
      for (int r = 0; r < 16; r++){
        const float4 h4 = *(const float4*)(&hsbuf[(kh*16+r)*260 + j]);
        accm[r] += h4.x*w0; accm[r] += h4.y*w1v; accm[r] += h4.z*w2v; accm[r] += h4.w*w3;
      }
    }
    float accs[16] = {};
    for (int j = 0; j < 64; j += 4){
      float w0 = wsc[j*128+c], w1v = wsc[(j+1)*128+c];
      float w2v = wsc[(j+2)*128+c], w3 = wsc[(j+3)*128+c];
      for (int r = 0; r < 16; r++){
        const float4 p4 = *(const float4*)(&xs[kh*16+r][64+j]);
        accs[r] += p4.x*w0; accs[r] += p4.y*w1v; accs[r] += p4.z*w2v; accs[r] += p4.w*w3;
      }
    }
    float mx = -1e30f;
    for (int r = 0; r < 16; r++){
      float mainv = accm[r]*a2 + d2v;
      float scv = fmaxf(accs[r]*asc + dscv, 0.f);
      mx = fmaxf(mx, fmaxf(mainv + scv, 0.f));
    }
    red[t] = mx;
  }
  __syncthreads();
  if (t < 128){
    float m = fmaxf(red[t], red[t+128]);
    out[12288 + (size_t)g*128 + t] = m;
  }
}

// ----------------------------------------------------------------
extern "C" void kernel_launch(void* const* d_in, const int* in_sizes, int n_in,
                              void* d_out, int out_size, void* d_ws, size_t ws_size,
                              hipStream_t stream){
  (void)in_sizes; (void)n_in; (void)d_ws; (void)ws_size; (void)out_size;
  const float* xyz      = (const float*)d_in[0];
  const float* points   = (const float*)d_in[1];
  const int*   fstart   = (const int*)  d_in[2];
  const float* pos_w1   = (const float*)d_in[3];
  const float* pos_b1   = (const float*)d_in[4];
  const float* pos_bn1  = (const float*)d_in[5];
  const float* pos_w2   = (const float*)d_in[6];
  const float* pos_b2   = (const float*)d_in[7];
  const float* pos_bn2  = (const float*)d_in[8];
  const float* nsa_wq   = (const float*)d_in[9];
  const float* nsa_bq   = (const float*)d_in[10];
  const float* nsa_wk   = (const float*)d_in[11];
  const float* nsa_bk   = (const float*)d_in[12];
  const float* nsa_wv   = (const float*)d_in[13];
  const float* nsa_bv   = (const float*)d_in[14];
  const float* nsa_g    = (const float*)d_in[15];
  const float* gam_g    = (const float*)d_in[16];
  const float* cat_w1   = (const float*)d_in[17];
  const float* cat_b1   = (const float*)d_in[18];
  const float* cat_bn1  = (const float*)d_in[19];
  const float* cat_w2   = (const float*)d_in[20];
  const float* cat_b2   = (const float*)d_in[21];
  const float* cat_bn2  = (const float*)d_in[22];
  const float* sc_w     = (const float*)d_in[23];
  const float* sc_b     = (const float*)d_in[24];
  const float* sc_bn    = (const float*)d_in[25];
  float* out = (float*)d_out;   // OUTPUT IS FLOAT32 (decoded round 11)

  k_fps     <<<NB, 256, 0, stream>>>(xyz, fstart, out);
  k_knn     <<<NB*NS, 256, 0, stream>>>(xyz);
  k_posembed<<<512, 256, 0, stream>>>(xyz, pos_w1, pos_b1, pos_bn1, pos_w2, pos_b2, pos_bn2);
  k_gram    <<<dim3(64, NB), 256, 0, stream>>>(points);
  k_softmax <<<NB*NS, 256, 0, stream>>>();
  k_grp     <<<dim3(512, NB), 256, 0, stream>>>(points);
  k_final   <<<dim3(512, NB), 256, 0, stream>>>(points,
              nsa_wq, nsa_bq, nsa_wk, nsa_bk, nsa_wv, nsa_bv, nsa_g, gam_g,
              cat_w1, cat_b1, cat_bn1, cat_w2, cat_b2, cat_bn2,
              sc_w, sc_b, sc_bn, out);
}

// Round 13
// 2823.973 us; speedup vs baseline: 1.0000x; 1.0000x over previous
//
#include <hip/hip_runtime.h>
#include <stdint.h>
#include <float.h>

typedef unsigned int uint;

#define NB 8
#define NPTS 4096
#define NS 512
#define NKN 32

// ---- static device scratch (~177 MB, allocated at module load; fully rewritten each call)
__device__ int   g_fps_idx[NB*NS];
__device__ int   g_knn_idx[NB*NS*NKN];
__device__ float g_knn_d2 [NB*NS*NKN];
__device__ float g_posb   [(size_t)NB*NS*NKN*64];    //  33.5 MB
__device__ float g_ga     [(size_t)NB*NS*NS];        //   8.4 MB
__device__ float g_dsa    [(size_t)NB*NS*NKN*256];   // 134 MB  [group*32+k][256] = [nei|grp]

__device__ __forceinline__ unsigned long long shfl_down_u64(unsigned long long v, int off){
  int lo = __shfl_down((int)(unsigned)v, off);
  int hi = __shfl_down((int)(unsigned)(v >> 32), off);
  return ((unsigned long long)(unsigned)hi << 32) | (unsigned)lo;
}
__device__ __forceinline__ double shfl_down_f64(double v, int off){
  return __longlong_as_double((long long)shfl_down_u64((unsigned long long)__double_as_longlong(v), off));
}
__device__ __forceinline__ void ldf8(const float* p, float* d){
  float4 a = *(const float4*)p, b = *(const float4*)(p+4);
  d[0]=a.x; d[1]=a.y; d[2]=a.z; d[3]=a.w; d[4]=b.x; d[5]=b.y; d[6]=b.z; d[7]=b.w;
}
// robust start read: int32 (start[b]) vs int64 (start[2b]; high words zero since values<4096)
__device__ __forceinline__ int read_start(const int* __restrict__ start, int b){
  int w1 = start[1], w3 = start[3], w5 = start[5], w7 = start[7];
  bool is64 = ((w1 | w3 | w5 | w7) == 0);
  int v = is64 ? start[2*b] : start[b];
  return v & (NPTS - 1);
}

// flat column order: n = k*128 + d, d<64 -> posb, d>=64 -> points gather
__device__ __forceinline__ void load_flat8(const float* __restrict__ points,
                                           int b, int row, int n, float* d){
  const int k = n >> 7, col = n & 63;
  if (n & 64){
    const int idx = g_knn_idx[((b << 9) + row)*32 + k];
    ldf8(points + (((size_t)b << 12) + idx)*64 + col, d);
  } else {
    ldf8(g_posb + (((size_t)((b << 9) + row))*32 + k)*64 + col, d);
  }
}
__device__ __forceinline__ float4 load_flat4(const float* __restrict__ points,
                                             int b, int row, int n){
  const int k = n >> 7, d = n & 127;
  if (d & 64){
    const int idx = g_knn_idx[((b << 9) + row)*32 + k];
    return *(const float4*)(points + (((size_t)b << 12) + idx)*64 + (d & 63));
  } else {
    return *(const float4*)(g_posb + (((size_t)((b << 9) + row))*32 + k)*64 + d);
  }
}
// reorganized order for Gram only: kc in [0,2048) pos (k-major), [2048,4096) pts
__device__ __forceinline__ void load_gram8(const float* __restrict__ points,
                                           int b, int row, int kc, float* d){
  if (kc < 2048){
    ldf8(g_posb + ((size_t)((b << 9) + row))*2048 + kc, d);
  } else {
    const int kc2 = kc - 2048, kg = kc2 >> 6, col = kc2 & 63;
    const int idx = g_knn_idx[((b << 9) + row)*32 + kg];
    ldf8(points + (((size_t)b << 12) + idx)*64 + col, d);
  }
}

// ---------------------------------------------------------------- FPS (f64 selection, 1024 thr)
__global__ __launch_bounds__(1024) void k_fps(const float* __restrict__ xyz,
                                              const int* __restrict__ start,
                                              float* __restrict__ center_out){
#pragma clang fp contract(off)
  const int b = blockIdx.x, tid = threadIdx.x;
  const float* X = xyz + (size_t)b * NPTS * 3;
  __shared__ float sx[NPTS], sy[NPTS], sz[NPTS];
  for (int p = tid; p < NPTS; p += 1024){
    sx[p] = X[3*p]; sy[p] = X[3*p+1]; sz[p] = X[3*p+2];
  }
  __shared__ int s_start0;
  if (tid == 0) s_start0 = read_start(start, b);
  __syncthreads();
  float px[4], py[4], pz[4];
  double dist[4];
  for (int i = 0; i < 4; i++){
    int p = tid*4 + i;
    px[i] = sx[p]; py[i] = sy[p]; pz[i] = sz[p];
    dist[i] = 1e10;
  }
  __shared__ double s_v[16]; __shared__ int s_i[16]; __shared__ int s_cur;
  int cur = s_start0;
  for (int t = 0; t < NS; t++){
    if (tid == 0){
      g_fps_idx[b*NS + t] = cur;
      center_out[(size_t)(b*NS + t)*3 + 0] = sx[cur];
      center_out[(size_t)(b*NS + t)*3 + 1] = sy[cur];
      center_out[(size_t)(b*NS + t)*3 + 2] = sz[cur];
    }
    const double cx = (double)sx[cur], cy = (double)sy[cur], cz = (double)sz[cur];
    double bv = -1.0; int bi = 0;
    for (int i = 0; i < 4; i++){
      double dx = (double)px[i]-cx, dy = (double)py[i]-cy, dz = (double)pz[i]-cz;
      double d = ((dx*dx) + (dy*dy)) + (dz*dz);
      dist[i] = fmin(dist[i], d);
      if (dist[i] > bv){ bv = dist[i]; bi = tid*4 + i; }
    }
    for (int off = 32; off; off >>= 1){
      double ov = shfl_down_f64(bv, off); int oi = __shfl_down(bi, off);
      if (ov > bv || (ov == bv && oi < bi)){ bv = ov; bi = oi; }
    }
    if ((tid & 63) == 0){ s_v[tid>>6] = bv; s_i[tid>>6] = bi; }
    __syncthreads();
    if (tid < 64){
      double v2 = (tid < 16) ? s_v[tid] : -1.0;
      int    i2 = (tid < 16) ? s_i[tid] : 0x7fffffff;
      for (int off = 8; off; off >>= 1){
        double ov = shfl_down_f64(v2, off); int oi = __shfl_down(i2, off);
        if (ov > v2 || (ov == v2 && oi < i2)){ v2 = ov; i2 = oi; }
      }
      if (tid == 0) s_cur = i2;
    }
    __syncthreads();
    cur = s_cur;
  }
}

// ---------------------------------------------------------------- KNN top-32 (f64, lexicographic (d2,idx))
__global__ __launch_bounds__(256) void k_knn(const float* __restrict__ xyz){
#pragma clang fp contract(off)
  const int g = blockIdx.x;            // b*512 + s
  const int b = g >> 9;
  const int tid = threadIdx.x;
  const float* X = xyz + (size_t)b * NPTS * 3;
  const int cidx = g_fps_idx[g];
  const double cx = (double)X[3*cidx], cy = (double)X[3*cidx+1], cz = (double)X[3*cidx+2];
  const double cs = ((cx*cx) + (cy*cy)) + (cz*cz);
  double dl[16];
  for (int i = 0; i < 16; i++){
    int p = tid*16 + i;
    double x = (double)X[3*p], y = (double)X[3*p+1], z = (double)X[3*p+2];
    double xs = ((x*x) + (y*y)) + (z*z);
    double dt = ((cx*x) + (cy*y)) + (cz*z);
    dl[i] = (cs + xs) - 2.0*dt;
  }
  __shared__ double s_kd[4]; __shared__ int s_ki[4];
  __shared__ double s_wd;   __shared__ int s_wi;
  double lastd = -DBL_MAX; int lasti = -1;
  for (int sel = 0; sel < NKN; sel++){
    double bd = DBL_MAX; int bi = 0x7fffffff;
    for (int i = 0; i < 16; i++){
      int p = tid*16 + i;
      double d = dl[i];
      bool gt_last = (d > lastd) || (d == lastd && p > lasti);
      bool lt_best = (d < bd)    || (d == bd    && p < bi);
      if (gt_last && lt_best){ bd = d; bi = p; }
    }
    for (int off = 32; off; off >>= 1){
      double od = shfl_down_f64(bd, off); int oi = __shfl_down(bi, off);
      if (od < bd || (od == bd && oi < bi)){ bd = od; bi = oi; }
    }
    if ((tid & 63) == 0){ s_kd[tid>>6] = bd; s_ki[tid>>6] = bi; }
    __syncthreads();
    if (tid == 0){
      double md = s_kd[0]; int mi = s_ki[0];
      for (int w = 1; w < 4; w++){
        if (s_kd[w] < md || (s_kd[w] == md && s_ki[w] < mi)){ md = s_kd[w]; mi = s_ki[w]; }
      }
      s_wd = md; s_wi = mi;
      g_knn_idx[g*NKN + sel] = mi;
      g_knn_d2 [g*NKN + sel] = (float)md;
    }
    __syncthreads();
    lastd = s_wd; lasti = s_wi;
    __syncthreads();
  }
}

// ---------------------------------------------------------------- pos-embed MLP -> g_posb (f32)
__global__ __launch_bounds__(256) void k_posembed(
    const float* __restrict__ xyz,
    const float* __restrict__ w1, const float* __restrict__ b1, const float* __restrict__ bn1,
    const float* __restrict__ w2, const float* __restrict__ b2, const float* __restrict__ bn2){
  __shared__ float w1s[320], a1s[32], d1s[32], w2s[2048], a2s[64], d2s[64];
  const int t = threadIdx.x;
  for (int i = t; i < 320; i += 256) w1s[i] = w1[i];
  for (int i = t; i < 2048; i += 256) w2s[i] = w2[i];
  if (t < 32){
    float g = bn1[t], be = bn1[32+t], m = bn1[64+t], v = bn1[96+t];
    float a = g * rsqrtf(v + 1e-5f);
    a1s[t] = a; d1s[t] = b1[t]*a + (be - m*a);
  }
  if (t < 64){
    float g = bn2[t], be = bn2[64+t], m = bn2[128+t], v = bn2[192+t];
    float a = g * rsqrtf(v + 1e-5f);
    a2s[t] = a; d2s[t] = b2[t]*a + (be - m*a);
  }
  __syncthreads();
  const int row = blockIdx.x*256 + t;          // (b*512+s)*32 + k
  const int b = row >> 14;
  const int g = row >> 5;
  const float* X = xyz + (size_t)b * NPTS * 3;
  const int ci = g_fps_idx[g];
  const int ni = g_knn_idx[row];
  float c0 = X[3*ci], c1 = X[3*ci+1], c2 = X[3*ci+2];
  float n0 = X[3*ni], n1 = X[3*ni+1], n2 = X[3*ni+2];
  float feat[10] = {c0,c1,c2, n0,n1,n2, n0-c0,n1-c1,n2-c2, g_knn_d2[row]};
  float h[32];
  for (int o = 0; o < 32; o++){
    float acc = 0.f;
    for (int j = 0; j < 10; j++) acc += feat[j]*w1s[j*32+o];
    h[o] = fmaxf(acc*a1s[o] + d1s[o], 0.f);
  }
  float* xr = g_posb + (size_t)row * 64;
  for (int o = 0; o < 64; o++){
    float acc = 0.f;
    for (int j = 0; j < 32; j++) acc += h[j]*w2s[j*64+o];
    xr[o] = fmaxf(acc*a2s[o] + d2s[o], 0.f);
  }
}

// ---------------------------------------------------------------- Gram = flat @ flat^T (f32)
__global__ __launch_bounds__(256) void k_gram(const float* __restrict__ points){
  const int b = blockIdx.y;
  const int i0 = (blockIdx.x >> 3) * 64, j0 = (blockIdx.x & 7) * 64;
  __shared__ float As[32][68];
  __shared__ float Bs[32][68];
  const int t = threadIdx.x, tx = t & 15, ty = t >> 4;
  float acc[4][4] = {};
  for (int k0 = 0; k0 < 4096; k0 += 32){
    {
      int r = t >> 2, kk = (t & 3) * 8;
      float ta[8], tb[8];
      load_gram8(points, b, i0+r, k0+kk, ta);
      load_gram8(points, b, j0+r, k0+kk, tb);
      for (int jj = 0; jj < 8; jj++){ As[kk+jj][r] = ta[jj]; Bs[kk+jj][r] = tb[jj]; }
    }
    __syncthreads();
    for (int kk = 0; kk < 32; kk++){
      const float4 a4 = *(const float4*)(&As[kk][ty*4]);
      const float4 b4 = *(const float4*)(&Bs[kk][tx*4]);
      const float ar[4] = {a4.x,a4.y,a4.z,a4.w};
      const float br[4] = {b4.x,b4.y,b4.z,b4.w};
      for (int ia = 0; ia < 4; ia++)
        for (int ib = 0; ib < 4; ib++) acc[ia][ib] += ar[ia]*br[ib];
    }
    __syncthreads();
  }
  float* C = g_ga + (size_t)b * NS * NS;
  for (int ia = 0; ia < 4; ia++){
    float4 o = {acc[ia][0], acc[ia][1], acc[ia][2], acc[ia][3]};
    *(float4*)(C + (size_t)(i0+ty*4+ia)*NS + j0 + tx*4) = o;
  }
}

// ---------------------------------------------------------------- row softmax (in place)
__global__ __launch_bounds__(256) void k_softmax(){
  float* R = g_ga + (size_t)blockIdx.x * NS;
  const int t = threadIdx.x;
  float v0 = R[t], v1 = R[t+256];
  __shared__ float sm[4], ssum[4];
  float m = fmaxf(v0, v1);
  for (int off = 32; off; off >>= 1) m = fmaxf(m, __shfl_down(m, off));
  if ((t & 63) == 0) sm[t>>6] = m;
  __syncthreads();
  float mm = fmaxf(fmaxf(sm[0], sm[1]), fmaxf(sm[2], sm[3]));
  float e0 = expf(v0 - mm), e1 = expf(v1 - mm);
  float s = e0 + e1;
  for (int off = 32; off; off >>= 1) s += __shfl_down(s, off);
  if ((t & 63) == 0) ssum[t>>6] = s;
  __syncthreads();
  float inv = 1.0f / (ssum[0]+ssum[1]+ssum[2]+ssum[3]);
  R[t] = e0*inv; R[t+256] = e1*inv;
}

// ---------------------------------------------------------------- grp: ga @ flat, fused gamma*+x -> g_dsa[...,128:256]
__global__ __launch_bounds__(256) void k_grp(const float* __restrict__ points,
                                             const float* __restrict__ gam_g){
  const int b = blockIdx.y;
  const int s0 = (blockIdx.x >> 6) * 64, n0 = (blockIdx.x & 63) * 64;
  const float* G = g_ga + (size_t)b * NS * NS;
  __shared__ float As[32][68];
  __shared__ float Bs[32][68];
  const int t = threadIdx.x, tx = t & 15, ty = t >> 4;
  float acc[4][4] = {};
  for (int k0 = 0; k0 < NS; k0 += 32){
    {
      int r = t >> 2, kk = (t & 3) * 8;
      const float* pa = G + (size_t)(s0+r)*NS + k0 + kk;
      float4 v0 = *(const float4*)pa, v1 = *(const float4*)(pa+4);
      As[kk+0][r]=v0.x; As[kk+1][r]=v0.y; As[kk+2][r]=v0.z; As[kk+3][r]=v0.w;
      As[kk+4][r]=v1.x; As[kk+5][r]=v1.y; As[kk+6][r]=v1.z; As[kk+7][r]=v1.w;
      int k2 = t >> 3, c = (t & 7) * 8;
      float tb[8];
      load_flat8(points, b, k0+k2, n0+c, tb);
      for (int jj = 0; jj < 8; jj++) Bs[k2][c+jj] = tb[jj];
    }
    __syncthreads();
    for (int kk = 0; kk < 32; kk++){
      const float4 a4 = *(const float4*)(&As[kk][ty*4]);
      const float4 b4 = *(const float4*)(&Bs[kk][tx*4]);
      const float ar[4] = {a4.x,a4.y,a4.z,a4.w};
      const float br[4] = {b4.x,b4.y,b4.z,b4.w};
      for (int ia = 0; ia < 4; ia++)
        for (int ib = 0; ib < 4; ib++) acc[ia][ib] += ar[ia]*br[ib];
    }
    __syncthreads();
  }
  const float gmg = gam_g[0];
  const int n = n0 + tx*4;
  const int kq = n >> 7, dq = n & 127;
  for (int ia = 0; ia < 4; ia++){
    int s = s0 + ty*4 + ia;
    float4 xv = load_flat4(points, b, s, n);
    float4 o = {gmg*acc[ia][0]+xv.x, gmg*acc[ia][1]+xv.y,
                gmg*acc[ia][2]+xv.z, gmg*acc[ia][3]+xv.w};
    *(float4*)(g_dsa + ((size_t)((b*NS + s)*32 + kq))*256 + 128 + dq) = o;
  }
}

// ---------------------------------------------------------------- NSA: Q/K/V + softmax + PV -> g_dsa[...,0:128]
__global__ __launch_bounds__(256) void k_nsa(const float* __restrict__ points,
    const float* __restrict__ wq, const float* __restrict__ bq,
    const float* __restrict__ wk, const float* __restrict__ bk,
    const float* __restrict__ wv, const float* __restrict__ bv_,
    const float* __restrict__ nsa_g){
  const int g = blockIdx.y*512 + blockIdx.x;
  const int t = threadIdx.x, b = g >> 9;
  __shared__ float xs[32][132];
  __shared__ float vs[32][132];
  __shared__ float qs[32][17], ks[32][17];
  __shared__ float at[32][33];
  {
    int r = t >> 3, c8 = (t & 7) * 8;
    float tmp[8];
    ldf8(g_posb + ((size_t)g*32 + r)*64 + c8, tmp);
    for (int j = 0; j < 8; j++) xs[r][c8+j] = tmp[j];
    int idx = g_knn_idx[g*32 + r];
    ldf8(points + ((size_t)b*NPTS + idx)*64 + c8, tmp);
    for (int j = 0; j < 8; j++) xs[r][64+c8+j] = tmp[j];
  }
  __syncthreads();
  {
    int r = t >> 3, c = t & 7;
    float aq0 = bq[c], aq1 = bq[c+8], ak0 = bk[c], ak1 = bk[c+8];
    for (int j = 0; j < 128; j++){
      float xv = xs[r][j];
      aq0 += xv * wq[j*16+c];
      aq1 += xv * wq[j*16+c+8];
      ak0 += xv * wk[j*16+c];
      ak1 += xv * wk[j*16+c+8];
    }
    qs[r][c] = aq0; qs[r][c+8] = aq1; ks[r][c] = ak0; ks[r][c+8] = ak1;
  }
  {
    int r = t >> 3, cb = (t & 7) * 16;
    float acc[16];
    for (int i = 0; i < 16; i++) acc[i] = bv_[cb+i];
    for (int j = 0; j < 128; j++){
      float xv = xs[r][j];
      const float4* w4 = (const float4*)(wv + j*128 + cb);
      float4 wa = w4[0], wb = w4[1], wc = w4[2], wd = w4[3];
      acc[0] += xv*wa.x;  acc[1] += xv*wa.y;  acc[2] += xv*wa.z;  acc[3] += xv*wa.w;
      acc[4] += xv*wb.x;  acc[5] += xv*wb.y;  acc[6] += xv*wb.z;  acc[7] += xv*wb.w;
      acc[8] += xv*wc.x;  acc[9] += xv*wc.y;  acc[10]+= xv*wc.z;  acc[11]+= xv*wc.w;
      acc[12]+= xv*wd.x;  acc[13]+= xv*wd.y;  acc[14]+= xv*wd.z;  acc[15]+= xv*wd.w;
    }
    for (int i = 0; i < 16; i++) vs[r][cb+i] = acc[i];
  }
  __syncthreads();
  {
    int r = t >> 3, jb = (t & 7) * 4;
    for (int jj = 0; jj < 4; jj++){
      int j = jb + jj; float acc = 0.f;
      for (int c = 0; c < 16; c++) acc += qs[r][c] * ks[j][c];
      at[r][j] = acc;
    }
  }
  __syncthreads();
  if (t < 32){
    float m = -1e30f;
    for (int j = 0; j < 32; j++) m = fmaxf(m, at[t][j]);
    float e[32]; float sum = 0.f;
    for (int j = 0; j < 32; j++){ e[j] = expf(at[t][j] - m); sum += e[j]; }
    float inv = 1.0f / sum;
    for (int j = 0; j < 32; j++) at[t][j] = e[j]*inv;
  }
  __syncthreads();
  {
    int r = t >> 3, cb = (t & 7) * 16;
    const float gmn = nsa_g[0];
    float acc[16] = {};
    for (int j = 0; j < 32; j++){
      float a = at[r][j];
      for (int i = 0; i < 16; i++) acc[i] += a * vs[j][cb+i];
    }
    float* dst = g_dsa + ((size_t)g*32 + r)*256 + cb;
    for (int q = 0; q < 4; q++){
      float4 o = {gmn*acc[4*q+0] + xs[r][cb+4*q+0],
                  gmn*acc[4*q+1] + xs[r][cb+4*q+1],
                  gmn*acc[4*q+2] + xs[r][cb+4*q+2],
                  gmn*acc[4*q+3] + xs[r][cb+4*q+3]};
      *(float4*)(dst + 4*q) = o;
    }
  }
}

// ---------------------------------------------------------------- cat MLP + shortcut + maxpool -> out
__global__ __launch_bounds__(256) void k_mlp(const float* __restrict__ points,
    const float* __restrict__ w1, const float* __restrict__ b1, const float* __restrict__ bn1,
    const float* __restrict__ w2, const float* __restrict__ b2, const float* __restrict__ bn2,
    const float* __restrict__ wsc, const float* __restrict__ bsc, const float* __restrict__ bnsc,
    float* __restrict__ out){
  const int g = blockIdx.y*512 + blockIdx.x;
  const int t = threadIdx.x, b = g >> 9;
  __shared__ float ds[32][260];
  __shared__ float hs[32][260];
  __shared__ float ps[32][68];
  __shared__ float a1s[256], d1s[256];
  __shared__ float red[256];
  for (int i = t; i < 2048; i += 256){
    int r = i >> 6, c = (i & 63) * 4;
    *(float4*)(&ds[r][c]) = *(const float4*)(g_dsa + ((size_t)g*32 + r)*256 + c);
  }
  for (int i = t; i < 512; i += 256){
    int r = i >> 4, c = (i & 15) * 4;
    int idx = g_knn_idx[g*32 + r];
    *(float4*)(&ps[r][c]) = *(const float4*)(points + ((size_t)b*NPTS + idx)*64 + c);
  }
  {
    float gg2 = bn1[t], be = bn1[256+t], m = bn1[512+t], v = bn1[768+t];
    float a = gg2 * rsqrtf(v + 1e-5f);
    a1s[t] = a; d1s[t] = b1[t]*a + (be - m*a);
  }
  __syncthreads();
  // C1: h = relu(bn1(dsa @ W1 + b1))
  {
    const int kg = t >> 6, c0 = (t & 63) * 4;
    float acc[8][4] = {};
    for (int j = 0; j < 256; j += 4){
      float wvv[4][4];
      for (int jj = 0; jj < 4; jj++){
        float4 wrow = *(const float4*)(w1 + (j+jj)*256 + c0);
        wvv[jj][0] = wrow.x; wvv[jj][1] = wrow.y; wvv[jj][2] = wrow.z; wvv[jj][3] = wrow.w;
      }
      for (int r = 0; r < 8; r++){
        const float4 d4 = *(const float4*)(&ds[kg*8+r][j]);
        const float dr[4] = {d4.x, d4.y, d4.z, d4.w};
        for (int jj = 0; jj < 4; jj++)
          for (int i = 0; i < 4; i++) acc[r][i] += dr[jj]*wvv[jj][i];
      }
    }
    for (int r = 0; r < 8; r++){
      float4 o;
      o.x = fmaxf(acc[r][0]*a1s[c0+0] + d1s[c0+0], 0.f);
      o.y = fmaxf(acc[r][1]*a1s[c0+1] + d1s[c0+1], 0.f);
      o.z = fmaxf(acc[r][2]*a1s[c0+2] + d1s[c0+2], 0.f);
      o.w = fmaxf(acc[r][3]*a1s[c0+3] + d1s[c0+3], 0.f);
      *(float4*)(&hs[kg*8+r][c0]) = o;
    }
  }
  __syncthreads();
  // C2: layer 2 + shortcut + relu + max over k
  {
    const int c = t & 127, kh = t >> 7;
    float g2 = bn2[c], be2 = bn2[128+c], m2 = bn2[256+c], v2 = bn2[384+c];
    float a2 = g2 * rsqrtf(v2 + 1e-5f);
    float d2v = b2[c]*a2 + (be2 - m2*a2);
    float gsc = bnsc[c], besc = bnsc[128+c], msc = bnsc[256+c], vsc = bnsc[384+c];
    float asc = gsc * rsqrtf(vsc + 1e-5f);
    float dscv = bsc[c]*asc + (besc - msc*asc);
    float accm[16] = {};
    for (int j = 0; j < 256; j += 4){
      float w0 = w2[j*128+c], w1v = w2[(j+1)*128+c];
      float w2v = w2[(j+2)*128+c], w3 = w2[(j+3)*128+c];
      for (int r = 0; r < 16; r++){
        const float4 h4 = *(const float4*)(&hs[kh*16+r][j]);
        accm[r] += h4.x*w0; accm[r] += h4.y*w1v; accm[r] += h4.z*w2v; accm[r] += h4.w*w3;
      }
    }
    float accs[16] = {};
    for (int j = 0; j < 64; j += 4){
      float w0 = wsc[j*128+c], w1v = wsc[(j+1)*128+c];
      float w2v = wsc[(j+2)*128+c], w3 = wsc[(j+3)*128+c];
      for (int r = 0; r < 16; r++){
        const float4 p4 = *(const float4*)(&ps[kh*16+r][j]);
        accs[r] += p4.x*w0; accs[r] += p4.y*w1v; accs[r] += p4.z*w2v; accs[r] += p4.w*w3;
      }
    }
    float mx = -1e30f;
    for (int r = 0; r < 16; r++){
      float mainv = accm[r]*a2 + d2v;
      float scv = fmaxf(accs[r]*asc + dscv, 0.f);
      mx = fmaxf(mx, fmaxf(mainv + scv, 0.f));
    }
    red[t] = mx;
  }
  __syncthreads();
  if (t < 128){
    float m = fmaxf(red[t], red[t+128]);
    out[12288 + (size_t)g*128 + t] = m;
  }
}

// ----------------------------------------------------------------
extern "C" void kernel_launch(void* const* d_in, const int* in_sizes, int n_in,
                              void* d_out, int out_size, void* d_ws, size_t ws_size,
                              hipStream_t stream){
  (void)in_sizes; (void)n_in; (void)d_ws; (void)ws_size; (void)out_size;
  const float* xyz      = (const float*)d_in[0];
  const float* points   = (const float*)d_in[1];
  const int*   fstart   = (const int*)  d_in[2];
  const float* pos_w1   = (const float*)d_in[3];
  const float* pos_b1   = (const float*)d_in[4];
  const float* pos_bn1  = (const float*)d_in[5];
  const float* pos_w2   = (const float*)d_in[6];
  const float* pos_b2   = (const float*)d_in[7];
  const float* pos_bn2  = (const float*)d_in[8];
  const float* nsa_wq   = (const float*)d_in[9];
  const float* nsa_bq   = (const float*)d_in[10];
  const float* nsa_wk   = (const float*)d_in[11];
  const float* nsa_bk   = (const float*)d_in[12];
  const float* nsa_wv   = (const float*)d_in[13];
  const float* nsa_bv   = (const float*)d_in[14];
  const float* nsa_g    = (const float*)d_in[15];
  const float* gam_g    = (const float*)d_in[16];
  const float* cat_w1   = (const float*)d_in[17];
  const float* cat_b1   = (const float*)d_in[18];
  const float* cat_bn1  = (const float*)d_in[19];
  const float* cat_w2   = (const float*)d_in[20];
  const float* cat_b2   = (const float*)d_in[21];
  const float* cat_bn2  = (const float*)d_in[22];
  const float* sc_w     = (const float*)d_in[23];
  const float* sc_b     = (const float*)d_in[24];
  const float* sc_bn    = (const float*)d_in[25];
  float* out = (float*)d_out;   // output is float32

  k_fps     <<<NB, 1024, 0, stream>>>(xyz, fstart, out);
  k_knn     <<<NB*NS, 256, 0, stream>>>(xyz);
  k_posembed<<<512, 256, 0, stream>>>(xyz, pos_w1, pos_b1, pos_bn1, pos_w2, pos_b2, pos_bn2);
  k_gram    <<<dim3(64, NB), 256, 0, stream>>>(points);
  k_softmax <<<NB*NS, 256, 0, stream>>>();
  k_grp     <<<dim3(512, NB), 256, 0, stream>>>(points, gam_g);
  k_nsa     <<<dim3(512, NB), 256, 0, stream>>>(points, nsa_wq, nsa_bq, nsa_wk, nsa_bk,
                                                nsa_wv, nsa_bv, nsa_g);
  k_mlp     <<<dim3(512, NB), 256, 0, stream>>>(points, cat_w1, cat_b1, cat_bn1,
                                                cat_w2, cat_b2, cat_bn2,
                                                sc_w, sc_b, sc_bn, out);
}